// Round 2
// baseline (448.101 us; speedup 1.0000x reference)
//
#include <hip/hip_runtime.h>

// Sparsemax along last dim of (8192 x 8192) fp32.
// Since sum(max(x-tau,0)) = 1 and max contributes <= 1, tau in [max-1, max).
// => support subset of {x > max-1} (~21 elements/row for N(0,1) data).
// Algorithm: block max -> collect candidates > max-1 to LDS -> per-wave
// Michelot on candidates (shuffle-only, no barriers) -> epilogue from regs.

#define D 8192
#define BLOCK 256
#define VEC 8    // float4s per thread = 32 elements
#define CAP 256  // candidate capacity; fallback if exceeded

typedef float v4f __attribute__((ext_vector_type(4)));

__global__ __launch_bounds__(BLOCK) void sparsemax_kernel(
    const float* __restrict__ x, float* __restrict__ out) {
  const long long row = blockIdx.x;
  const float4* __restrict__ xr = (const float4*)(x + row * (long long)D);
  float4* __restrict__ outr = (float4*)(out + row * (long long)D);
  const int tid = threadIdx.x;
  const int lane = tid & 63;
  const int wave = tid >> 6;

  __shared__ float red_a[4];
  __shared__ float red_b[4];
  __shared__ int s_cnt;
  __shared__ float cand[CAP];

  if (tid == 0) s_cnt = 0;

  // ---- load row into registers (coalesced float4) ----
  float4 v[VEC];
#pragma unroll
  for (int i = 0; i < VEC; ++i) v[i] = xr[tid + i * BLOCK];

  // ---- block max (one barrier) ----
  float m = -3.402823466e+38f;
#pragma unroll
  for (int i = 0; i < VEC; ++i)
    m = fmaxf(m, fmaxf(fmaxf(v[i].x, v[i].y), fmaxf(v[i].z, v[i].w)));
#pragma unroll
  for (int o = 1; o < 64; o <<= 1) m = fmaxf(m, __shfl_xor(m, o, 64));
  if (lane == 0) red_a[wave] = m;
  __syncthreads();  // barrier 1 (also orders s_cnt = 0)
  m = fmaxf(fmaxf(red_a[0], red_a[1]), fmaxf(red_a[2], red_a[3]));
  const float lo = m - 1.0f;  // tau >= lo always

  // ---- collect candidates x > lo into LDS ----
#pragma unroll
  for (int i = 0; i < VEC; ++i) {
    float4 c4 = v[i];
    if (c4.x > lo) { int p = atomicAdd(&s_cnt, 1); if (p < CAP) cand[p] = c4.x; }
    if (c4.y > lo) { int p = atomicAdd(&s_cnt, 1); if (p < CAP) cand[p] = c4.y; }
    if (c4.z > lo) { int p = atomicAdd(&s_cnt, 1); if (p < CAP) cand[p] = c4.z; }
    if (c4.w > lo) { int p = atomicAdd(&s_cnt, 1); if (p < CAP) cand[p] = c4.w; }
  }
  __syncthreads();  // barrier 2
  const int K = s_cnt;

  float tau;
  if (K <= CAP) {
    // Every wave independently solves on the candidate set: no more barriers.
    // Lane holds up to CAP/64 candidates in registers (invalid -> -inf).
    float e[CAP / 64];
#pragma unroll
    for (int j = 0; j < CAP / 64; ++j) {
      int idx = lane + j * 64;
      e[j] = (idx < K) ? cand[idx] : -3.402823466e+38f;
    }
    // initial tau over the full candidate set (superset of support)
    float s = 0.f, c = 0.f;
#pragma unroll
    for (int j = 0; j < CAP / 64; ++j)
      if (lane + j * 64 < K) { s += e[j]; c += 1.f; }
#pragma unroll
    for (int o = 1; o < 64; o <<= 1) {
      s += __shfl_xor(s, o, 64);
      c += __shfl_xor(c, o, 64);
    }
    tau = (s - 1.0f) / c;
    float prev = c;
    for (int it = 0; it < 300; ++it) {
      s = 0.f; c = 0.f;
#pragma unroll
      for (int j = 0; j < CAP / 64; ++j)
        if (e[j] > tau) { s += e[j]; c += 1.f; }
#pragma unroll
      for (int o = 1; o < 64; o <<= 1) {
        s += __shfl_xor(s, o, 64);
        c += __shfl_xor(c, o, 64);
      }
      tau = (s - 1.0f) / c;
      if (c == prev) break;  // support stable => tau exact
      prev = c;
    }
  } else {
    // Rare fallback (e.g. near-constant rows): block-wide Michelot over
    // registers, starting from the superset {x > lo}.
    float tl = lo, prev = -1.f;
    for (int it = 0; it < 64; ++it) {
      float s = 0.f, c = 0.f;
#pragma unroll
      for (int i = 0; i < VEC; ++i) {
        if (v[i].x > tl) { s += v[i].x; c += 1.f; }
        if (v[i].y > tl) { s += v[i].y; c += 1.f; }
        if (v[i].z > tl) { s += v[i].z; c += 1.f; }
        if (v[i].w > tl) { s += v[i].w; c += 1.f; }
      }
#pragma unroll
      for (int o = 1; o < 64; o <<= 1) {
        s += __shfl_xor(s, o, 64);
        c += __shfl_xor(c, o, 64);
      }
      if (lane == 0) { red_a[wave] = s; red_b[wave] = c; }
      __syncthreads();
      float ts = (red_a[0] + red_a[1]) + (red_a[2] + red_a[3]);
      float tc = (red_b[0] + red_b[1]) + (red_b[2] + red_b[3]);
      __syncthreads();  // red arrays reused next iteration
      tl = (ts - 1.0f) / tc;
      if (tc == prev) break;
      prev = tc;
    }
    tau = tl;
  }

  // ---- epilogue: out = max(x - tau, 0), nontemporal streaming stores ----
#pragma unroll
  for (int i = 0; i < VEC; ++i) {
    v4f o;
    o.x = fmaxf(v[i].x - tau, 0.f);
    o.y = fmaxf(v[i].y - tau, 0.f);
    o.z = fmaxf(v[i].z - tau, 0.f);
    o.w = fmaxf(v[i].w - tau, 0.f);
    __builtin_nontemporal_store(o, (v4f*)&outr[tid + i * BLOCK]);
  }
}

extern "C" void kernel_launch(void* const* d_in, const int* in_sizes, int n_in,
                              void* d_out, int out_size, void* d_ws, size_t ws_size,
                              hipStream_t stream) {
  const float* x = (const float*)d_in[0];
  float* out = (float*)d_out;
  const int rows = in_sizes[0] / D;  // 8192
  sparsemax_kernel<<<rows, BLOCK, 0, stream>>>(x, out);
}